// Round 5
// baseline (193.449 us; speedup 1.0000x reference)
//
#include <hip/hip_runtime.h>
#include <hip/hip_fp16.h>

#define TT    64        // output tokens per tile
#define HALO  9         // (KERNEL_SIZE-1)*DILATION
#define NTOK  73        // TT + HALO
#define XSTR  132       // s_xn row stride in halves (fused fallback)
#define VSTR  36        // s_val row stride in floats (fused fallback)
#define EPS   1.1920929e-07f

#define NTILES 2048     // 16 batches * 128 tiles of 64 tokens
#define GRID1  512      // persistent K1 blocks (2 per CU); 4 tiles each
#define GRID2  2048     // K2 blocks; 8 slabs each
#define K2_SLAB (GRID2 * 256)

typedef __attribute__((ext_vector_type(8))) _Float16 f16x8;
typedef __attribute__((ext_vector_type(4))) float f32x4;

// sum over each 16-lane row via DPP rotate-butterfly: pure VALU, no LDS pipe.
template<int CTRL>
__device__ __forceinline__ float dpp_add(float x) {
    int y = __builtin_amdgcn_update_dpp(0, __float_as_int(x), CTRL, 0xF, 0xF, true);
    return x + __int_as_float(y);
}
__device__ __forceinline__ float redsum16(float x) {
    x = dpp_add<0x128>(x);   // row_ror:8
    x = dpp_add<0x124>(x);   // row_ror:4
    x = dpp_add<0x122>(x);   // row_ror:2
    x = dpp_add<0x121>(x);   // row_ror:1
    return x;
}

__device__ __forceinline__ float fast_rcp(float x) {
    return __builtin_amdgcn_rcpf(x);
}

// ---- K1 register-staged tile (all indices compile-time in unrolled loops) ----
struct TileIn {
    float2 q2[4][4];     // hid fragments
    float4 f0, f1;       // emb A-fragment
};

struct Wgt {
    float2 bv2;
    float2 bk2[4], wn1[4], wn2[4], wcn[4];
};

__device__ __forceinline__ void tile_load(TileIn& T,
                                          const float* __restrict__ emb,
                                          const float* __restrict__ hid,
                                          int tileIdx, int wv, int l15, int q) {
    const int b  = tileIdx >> 7;
    const int tw = (tileIdx & 127) * 64 + wv * 16;   // wave's token base (in-range)
    #pragma unroll
    for (int r = 0; r < 4; ++r) {
        const int t = tw + q * 4 + r;
        const float2* qp = (const float2*)&hid[(size_t)((b << 13) + t) * 128];
        #pragma unroll
        for (int g = 0; g < 4; ++g) T.q2[r][g] = qp[g * 16 + l15];
    }
    const float4* p = (const float4*)&emb[(size_t)((b << 13) + tw + l15) * 32 + q * 8];
    T.f0 = p[0];
    T.f1 = p[1];
}

__device__ __forceinline__ void tile_compute(const TileIn& T, const Wgt& W,
                                             const float* __restrict__ Wv,
                                             const float* __restrict__ Wk,
                                             __half* __restrict__ xn_out,
                                             float* __restrict__ val_out,
                                             float* __restrict__ gate_out,
                                             int tileIdx, int wv, int l15, int q) {
    const int b  = tileIdx >> 7;
    const int tw = (tileIdx & 127) * 64 + wv * 16;

    // ======== MFMA: 10 tiles, permuted columns ========
    f16x8 a;
    a[0] = (_Float16)T.f0.x; a[1] = (_Float16)T.f0.y;
    a[2] = (_Float16)T.f0.z; a[3] = (_Float16)T.f0.w;
    a[4] = (_Float16)T.f1.x; a[5] = (_Float16)T.f1.y;
    a[6] = (_Float16)T.f1.z; a[7] = (_Float16)T.f1.w;

    // Tile nt = 2p+e: column l15 <- weight row ch = 2*l15+e of (p==0?Wv:Wk[p-1]).
    // Lane's D pair (D[2p],D[2p+1]) = channels (2*l15, 2*l15+1).
    f32x4 D[10];
    #pragma unroll
    for (int nt = 0; nt < 10; ++nt) {
        const int e = nt & 1, p = nt >> 1;
        const int ch = 2 * l15 + e;
        const float* wrow = (p == 0) ? &Wv[ch * 32] : &Wk[((p - 1) * 32 + ch) * 32];
        float4 w0 = ((const float4*)wrow)[q * 2];
        float4 w1 = ((const float4*)wrow)[q * 2 + 1];
        f16x8 bf;
        bf[0] = (_Float16)w0.x; bf[1] = (_Float16)w0.y;
        bf[2] = (_Float16)w0.z; bf[3] = (_Float16)w0.w;
        bf[4] = (_Float16)w1.x; bf[5] = (_Float16)w1.y;
        bf[6] = (_Float16)w1.z; bf[7] = (_Float16)w1.w;
        const float bias = (p == 0) ? (e ? W.bv2.y : W.bv2.x)
                                    : (e ? W.bk2[p - 1].y : W.bk2[p - 1].x);
        f32x4 c = {bias, bias, bias, bias};
        D[nt] = __builtin_amdgcn_mfma_f32_16x16x32_f16(a, bf, c, 0, 0, 0);
    }

    // ======== norms + gate + x_norm; stream straight to global ========
    #pragma unroll
    for (int r = 0; r < 4; ++r) {
        const int ti = tw + q * 4 + r;
        const float V0 = D[0][r], V1 = D[1][r];
        float msv = redsum16(V0 * V0 + V1 * V1);   // Σ value² over 32 ch
        float gs[4];
        float xnv[4][2];
        #pragma unroll
        for (int g = 0; g < 4; ++g) {
            const float K0 = D[2 + 2 * g][r], K1v = D[3 + 2 * g][r];
            const float q0 = T.q2[r][g].x, q1 = T.q2[r][g].y;
            float msk = redsum16(K0 * K0 + K1v * K1v);
            float msq = redsum16(q0 * q0 + q1 * q1);
            float dr  = redsum16(K0 * W.wn1[g].x * q0 * W.wn2[g].x
                               + K1v * W.wn1[g].y * q1 * W.wn2[g].y);
            float rk = rsqrtf(msk * (1.f / 32.f) + EPS);
            float rq = rsqrtf(msq * (1.f / 32.f) + EPS);
            float dot = dr * rk * rq * 0.17677669529663689f;   // /sqrt(32)
            float sa = sqrtf(fmaxf(fabsf(dot), 1e-6f));
            float gate = fast_rcp(1.f + __expf(-copysignf(sa, dot)));
            gs[g] = gate;
            float sc = gate * rsqrtf(gate * gate * msv * (1.f / 32.f) + EPS);
            xnv[g][0] = sc * V0 * W.wcn[g].x;
            xnv[g][1] = sc * V1 * W.wcn[g].y;
        }
        __half* xrow = xn_out + (size_t)((b << 13) + ti) * 128;
        #pragma unroll
        for (int g = 0; g < 4; ++g) {
            *(__half2*)&xrow[g * 32 + 2 * l15] = __floats2half2_rn(xnv[g][0], xnv[g][1]);
        }
        *(float2*)&val_out[(size_t)((b << 13) + ti) * 32 + 2 * l15] = make_float2(V0, V1);
        if (l15 < 4) {
            float gsel = (l15 == 0) ? gs[0] : (l15 == 1) ? gs[1]
                       : (l15 == 2) ? gs[2] : gs[3];
            gate_out[(size_t)((b << 13) + ti) * 4 + l15] = gsel;
        }
    }
}

// ===========================================================================
// K1: persistent (2 blocks/CU), 4 tiles per block, double-buffered register
// staging. NO LDS, NO barriers — every compute phase hides the other
// buffer's load latency. (256,2): VGPR cap 256, est. ~185 used.
// ===========================================================================
extern "C" __global__ __launch_bounds__(256, 2)
void engram_norm(const float* __restrict__ emb,   // [16,8192,32]
                 const float* __restrict__ hid,   // [16,8192,4,32]
                 const float* __restrict__ Wv,    // [32,32]
                 const float* __restrict__ bv,    // [32]
                 const float* __restrict__ Wk,    // [4,32,32]
                 const float* __restrict__ bk,    // [4,32]
                 const float* __restrict__ n1w,   // [4,32]
                 const float* __restrict__ n2w,   // [4,32]
                 const float* __restrict__ cnw,   // [4,32]
                 __half* __restrict__ xn_out,     // [16,8192,128] f16
                 float* __restrict__ val_out,     // [16,8192,32]
                 float* __restrict__ gate_out)    // [16,8192,4]
{
    const int tid = threadIdx.x;
    const int wv  = tid >> 6;     // 0..3 (wave = one 16-token MFMA m-tile)
    const int ln  = tid & 63;
    const int l15 = ln & 15;
    const int q   = ln >> 4;

    Wgt W;
    W.bv2 = ((const float2*)bv)[l15];
    #pragma unroll
    for (int g = 0; g < 4; ++g) {
        W.bk2[g] = ((const float2*)(bk  + g * 32))[l15];
        W.wn1[g] = ((const float2*)(n1w + g * 32))[l15];
        W.wn2[g] = ((const float2*)(n2w + g * 32))[l15];
        W.wcn[g] = ((const float2*)(cnw + g * 32))[l15];
    }

    const int i0 = blockIdx.x;            // tiles i0 + k*GRID1, k=0..3
    TileIn A, B;
    tile_load(A, emb, hid, i0,             wv, l15, q);
    tile_load(B, emb, hid, i0 + GRID1,     wv, l15, q);
    tile_compute(A, W, Wv, Wk, xn_out, val_out, gate_out, i0,             wv, l15, q);
    tile_load(A, emb, hid, i0 + 2 * GRID1, wv, l15, q);
    tile_compute(B, W, Wv, Wk, xn_out, val_out, gate_out, i0 + GRID1,     wv, l15, q);
    tile_load(B, emb, hid, i0 + 3 * GRID1, wv, l15, q);
    tile_compute(A, W, Wv, Wk, xn_out, val_out, gate_out, i0 + 2 * GRID1, wv, l15, q);
    tile_compute(B, W, Wv, Wk, xn_out, val_out, gate_out, i0 + 3 * GRID1, wv, l15, q);
}

// ===========================================================================
// K2: dilated depthwise conv + SiLU + gated residual. Grid-stride over 8
// contiguous slabs; conv weights are iteration-invariant (hoisted). No LDS.
// ===========================================================================
extern "C" __global__ __launch_bounds__(256)
void engram_conv(const __half* __restrict__ xn,   // [16,8192,128] f16
                 const float* __restrict__ val,   // [16,8192,32]
                 const float* __restrict__ gate,  // [16,8192,4]
                 const float* __restrict__ cw,    // [128,1,4]
                 float* __restrict__ out)         // [16,8192,128]
{
    const int tid = threadIdx.x;
    const int c4  = (tid & 31) << 2;   // channel quad — slab-stride keeps it fixed
    const int g   = c4 >> 5;

    const float4* cw4p = (const float4*)cw;
    const float4 w0 = cw4p[c4 + 0];
    const float4 w1 = cw4p[c4 + 1];
    const float4 w2 = cw4p[c4 + 2];
    const float4 w3 = cw4p[c4 + 3];

    int gid = blockIdx.x * 256 + tid;
    #pragma unroll
    for (int it = 0; it < 8; ++it, gid += K2_SLAB) {
        const int t = (gid >> 5) & 8191;
        const int b = gid >> 18;
        const size_t row = (size_t)((b << 13) + t);

        float y0 = 0.f, y1 = 0.f, y2 = 0.f, y3 = 0.f;
        #pragma unroll
        for (int k = 0; k < 4; ++k) {
            const int tp  = t - HALO + 3 * k;
            const float m = (tp >= 0) ? 1.f : 0.f;    // causal zero-pad
            const int tpc = tp < 0 ? 0 : tp;
            const float2 rv = *(const float2*)&xn[(size_t)((b << 13) + tpc) * 128 + c4];
            float2 a01 = __half22float2(*(const __half2*)&rv.x);
            float2 a23 = __half22float2(*(const __half2*)&rv.y);
            const float wk0 = (k == 0) ? w0.x : (k == 1) ? w0.y : (k == 2) ? w0.z : w0.w;
            const float wk1 = (k == 0) ? w1.x : (k == 1) ? w1.y : (k == 2) ? w1.z : w1.w;
            const float wk2 = (k == 0) ? w2.x : (k == 1) ? w2.y : (k == 2) ? w2.z : w2.w;
            const float wk3 = (k == 0) ? w3.x : (k == 1) ? w3.y : (k == 2) ? w3.z : w3.w;
            y0 = fmaf(m * a01.x, wk0, y0);
            y1 = fmaf(m * a01.y, wk1, y1);
            y2 = fmaf(m * a23.x, wk2, y2);
            y3 = fmaf(m * a23.y, wk3, y3);
        }
        const float gg = gate[row * 4 + g];
        const f32x4 v  = *(const f32x4*)&val[row * 32 + (c4 & 31)];
        float4 o;
        o.x = gg * v[0] + y0 * fast_rcp(1.f + __expf(-y0));
        o.y = gg * v[1] + y1 * fast_rcp(1.f + __expf(-y1));
        o.z = gg * v[2] + y2 * fast_rcp(1.f + __expf(-y2));
        o.w = gg * v[3] + y3 * fast_rcp(1.f + __expf(-y3));
        *(float4*)&out[row * 128 + c4] = o;
    }
}

// ===========================================================================
// Fallback: round-0 fused kernel (proven), used only if workspace too small.
// ===========================================================================
extern "C" __global__ __launch_bounds__(320, 3)
void engram_fused(const float* __restrict__ emb,
                  const float* __restrict__ hid,
                  const float* __restrict__ Wv,
                  const float* __restrict__ bv,
                  const float* __restrict__ Wk,
                  const float* __restrict__ bk,
                  const float* __restrict__ n1w,
                  const float* __restrict__ n2w,
                  const float* __restrict__ cnw,
                  const float* __restrict__ cw,
                  float* __restrict__ out)
{
    __shared__ __align__(16) __half s_xn[NTOK * XSTR];
    __shared__ __align__(16) float  s_val[TT * VSTR];
    __shared__ float  s_gate[TT * 4];

    const int tid  = threadIdx.x;
    const int b    = blockIdx.x >> 7;
    const int tile = blockIdx.x & 127;
    const int t0   = tile * TT;

    const int wv  = tid >> 6;
    const int ln  = tid & 63;
    const int l15 = ln & 15;
    const int q   = ln >> 4;
    const int ibase = wv * 16 + q * 4;

    float2 q2[4][4];
    float  okm[4];
    #pragma unroll
    for (int r = 0; r < 4; ++r) {
        int t = t0 - HALO + ibase + r;
        okm[r] = (t >= 0 && t < 8192) ? 1.f : 0.f;
        int tc = t < 0 ? 0 : (t > 8191 ? 8191 : t);
        const float2* qp = (const float2*)&hid[(size_t)((b << 13) + tc) * 128];
        #pragma unroll
        for (int g = 0; g < 4; ++g) q2[r][g] = qp[g * 16 + l15];
    }

    float4 f0, f1;
    float amask;
    {
        const int tA = t0 - HALO + wv * 16 + l15;
        amask = (tA >= 0 && tA < 8192) ? 1.f : 0.f;
        const int tAc = tA < 0 ? 0 : (tA > 8191 ? 8191 : tA);
        const float4* p = (const float4*)&emb[(size_t)((b << 13) + tAc) * 32 + q * 8];
        f0 = p[0];
        f1 = p[1];
    }

    const float2 bv2 = ((const float2*)bv)[l15];
    float2 bk2[4], wn1[4], wn2[4], wcn[4];
    #pragma unroll
    for (int g = 0; g < 4; ++g) {
        bk2[g] = ((const float2*)(bk  + g * 32))[l15];
        wn1[g] = ((const float2*)(n1w + g * 32))[l15];
        wn2[g] = ((const float2*)(n2w + g * 32))[l15];
        wcn[g] = ((const float2*)(cnw + g * 32))[l15];
    }

    f16x8 a;
    a[0] = (_Float16)(amask * f0.x); a[1] = (_Float16)(amask * f0.y);
    a[2] = (_Float16)(amask * f0.z); a[3] = (_Float16)(amask * f0.w);
    a[4] = (_Float16)(amask * f1.x); a[5] = (_Float16)(amask * f1.y);
    a[6] = (_Float16)(amask * f1.z); a[7] = (_Float16)(amask * f1.w);

    f32x4 D[10];
    #pragma unroll
    for (int nt = 0; nt < 10; ++nt) {
        const int e = nt & 1, p = nt >> 1;
        const int ch = 2 * l15 + e;
        const float* wrow = (p == 0) ? &Wv[ch * 32] : &Wk[((p - 1) * 32 + ch) * 32];
        float4 w0 = ((const float4*)wrow)[q * 2];
        float4 w1 = ((const float4*)wrow)[q * 2 + 1];
        f16x8 bf;
        bf[0] = (_Float16)w0.x; bf[1] = (_Float16)w0.y;
        bf[2] = (_Float16)w0.z; bf[3] = (_Float16)w0.w;
        bf[4] = (_Float16)w1.x; bf[5] = (_Float16)w1.y;
        bf[6] = (_Float16)w1.z; bf[7] = (_Float16)w1.w;
        const float bias = (p == 0) ? (e ? bv2.y : bv2.x)
                                    : (e ? bk2[p - 1].y : bk2[p - 1].x);
        f32x4 c = {bias, bias, bias, bias};
        D[nt] = __builtin_amdgcn_mfma_f32_16x16x32_f16(a, bf, c, 0, 0, 0);
    }

    #pragma unroll
    for (int r = 0; r < 4; ++r) {
        const int i = ibase + r;
        const float V0 = D[0][r], V1 = D[1][r];
        float msv = redsum16(V0 * V0 + V1 * V1);
        float gs[4];
        float xnv[4][2];
        #pragma unroll
        for (int g = 0; g < 4; ++g) {
            const float K0 = D[2 + 2 * g][r], K1v = D[3 + 2 * g][r];
            const float q0 = q2[r][g].x * okm[r], q1 = q2[r][g].y * okm[r];
            float msk = redsum16(K0 * K0 + K1v * K1v);
            float msq = redsum16(q0 * q0 + q1 * q1);
            float dr  = redsum16(K0 * wn1[g].x * q0 * wn2[g].x
                               + K1v * wn1[g].y * q1 * wn2[g].y);
            float rk = rsqrtf(msk * (1.f / 32.f) + EPS);
            float rq = rsqrtf(msq * (1.f / 32.f) + EPS);
            float dot = dr * rk * rq * 0.17677669529663689f;
            float sa = sqrtf(fmaxf(fabsf(dot), 1e-6f));
            float gate = fast_rcp(1.f + __expf(-copysignf(sa, dot)));
            gs[g] = gate;
            float sc = gate * rsqrtf(gate * gate * msv * (1.f / 32.f) + EPS);
            xnv[g][0] = sc * V0 * wcn[g].x;
            xnv[g][1] = sc * V1 * wcn[g].y;
        }
        if (i < NTOK) {
            #pragma unroll
            for (int g = 0; g < 4; ++g) {
                __half2 h2 = __floats2half2_rn(okm[r] * xnv[g][0], okm[r] * xnv[g][1]);
                *(__half2*)&s_xn[i * XSTR + g * 32 + 2 * l15] = h2;
            }
            if (i >= HALO) {
                const int j = i - HALO;
                *(float2*)&s_val[j * VSTR + 2 * l15] = make_float2(V0, V1);
                if (l15 < 4) {
                    float gsel = (l15 == 0) ? gs[0] : (l15 == 1) ? gs[1]
                               : (l15 == 2) ? gs[2] : gs[3];
                    s_gate[j * 4 + l15] = gsel;
                }
            }
        }
    }
    __syncthreads();

    const float4* cw4p = (const float4*)cw;
    for (int idx = tid; idx < TT * 32; idx += 320) {
        const int j  = idx >> 5;
        const int c4 = (idx & 31) << 2;
        float4 w0 = cw4p[c4 + 0];
        float4 w1 = cw4p[c4 + 1];
        float4 w2 = cw4p[c4 + 2];
        float4 w3 = cw4p[c4 + 3];
        float y0 = 0.f, y1 = 0.f, y2 = 0.f, y3 = 0.f;
        #pragma unroll
        for (int k = 0; k < 4; ++k) {
            const __half2* xp = (const __half2*)&s_xn[(j + 3 * k) * XSTR + c4];
            float2 a01 = __half22float2(xp[0]);
            float2 a23 = __half22float2(xp[1]);
            const float wk0 = (k == 0) ? w0.x : (k == 1) ? w0.y : (k == 2) ? w0.z : w0.w;
            const float wk1 = (k == 0) ? w1.x : (k == 1) ? w1.y : (k == 2) ? w1.z : w1.w;
            const float wk2 = (k == 0) ? w2.x : (k == 1) ? w2.y : (k == 2) ? w2.z : w2.w;
            const float wk3 = (k == 0) ? w3.x : (k == 1) ? w3.y : (k == 2) ? w3.z : w3.w;
            y0 = fmaf(a01.x, wk0, y0);
            y1 = fmaf(a01.y, wk1, y1);
            y2 = fmaf(a23.x, wk2, y2);
            y3 = fmaf(a23.y, wk3, y3);
        }
        const float g  = s_gate[j * 4 + (c4 >> 5)];
        const f32x4 v  = *(const f32x4*)&s_val[j * VSTR + (c4 & 31)];
        float4 o;
        o.x = g * v[0] + y0 * fast_rcp(1.f + __expf(-y0));
        o.y = g * v[1] + y1 * fast_rcp(1.f + __expf(-y1));
        o.z = g * v[2] + y2 * fast_rcp(1.f + __expf(-y2));
        o.w = g * v[3] + y3 * fast_rcp(1.f + __expf(-y3));
        *(float4*)&out[(size_t)((b << 13) + t0 + j) * 128 + c4] = o;
    }
}

extern "C" void kernel_launch(void* const* d_in, const int* in_sizes, int n_in,
                              void* d_out, int out_size, void* d_ws, size_t ws_size,
                              hipStream_t stream) {
    const float* emb = (const float*)d_in[0];
    const float* hid = (const float*)d_in[1];
    const float* Wv  = (const float*)d_in[2];
    const float* bvp = (const float*)d_in[3];
    const float* Wk  = (const float*)d_in[4];
    const float* bkp = (const float*)d_in[5];
    const float* n1  = (const float*)d_in[6];
    const float* n2  = (const float*)d_in[7];
    const float* cn  = (const float*)d_in[8];
    const float* cwp = (const float*)d_in[9];
    float* out = (float*)d_out;

    const size_t xn_bytes   = (size_t)16 * 8192 * 128 * sizeof(__half);  // 33.6 MB
    const size_t val_bytes  = (size_t)16 * 8192 * 32 * sizeof(float);    // 16.8 MB
    const size_t gate_bytes = (size_t)16 * 8192 * 4 * sizeof(float);     //  2.1 MB
    const size_t need = xn_bytes + val_bytes + gate_bytes;               // 52.4 MB

    if (d_ws != nullptr && ws_size >= need) {
        __half* xn  = (__half*)d_ws;
        float* val  = (float*)((char*)d_ws + xn_bytes);
        float* gate = (float*)((char*)d_ws + xn_bytes + val_bytes);
        engram_norm<<<dim3(GRID1), dim3(256), 0, stream>>>(
            emb, hid, Wv, bvp, Wk, bkp, n1, n2, cn, xn, val, gate);
        engram_conv<<<dim3(GRID2), dim3(256), 0, stream>>>(
            xn, val, gate, cwp, out);
    } else {
        engram_fused<<<dim3(16 * 128), dim3(320), 0, stream>>>(
            emb, hid, Wv, bvp, Wk, bkp, n1, n2, cn, cwp, out);
    }
}

// Round 6
// 184.133 us; speedup vs baseline: 1.0506x; 1.0506x over previous
//
#include <hip/hip_runtime.h>
#include <hip/hip_fp16.h>

#define TT    64        // output tokens per tile (fused fallback)
#define HALO  9         // (KERNEL_SIZE-1)*DILATION
#define NTOK  73        // TT + HALO
#define XSTR  132       // s_xn row stride in halves (fused fallback)
#define VSTR  36        // s_val row stride in floats (fused fallback)
#define EPS   1.1920929e-07f

#define GRID1  512      // K1: 512 WGs x 1024 thr (16 waves; 1 wave = 16 tokens)
#define GRID2  512      // K2: 512 WGs x 1024 thr; 8 slabs each
#define K2_SLAB (GRID2 * 1024)

typedef __attribute__((ext_vector_type(8))) _Float16 f16x8;
typedef __attribute__((ext_vector_type(4))) float f32x4;

// sum over each 16-lane row via DPP rotate-butterfly: pure VALU, no LDS pipe.
template<int CTRL>
__device__ __forceinline__ float dpp_add(float x) {
    int y = __builtin_amdgcn_update_dpp(0, __float_as_int(x), CTRL, 0xF, 0xF, true);
    return x + __int_as_float(y);
}
__device__ __forceinline__ float redsum16(float x) {
    x = dpp_add<0x128>(x);   // row_ror:8
    x = dpp_add<0x124>(x);   // row_ror:4
    x = dpp_add<0x122>(x);   // row_ror:2
    x = dpp_add<0x121>(x);   // row_ror:1
    return x;
}

__device__ __forceinline__ float fast_rcp(float x) {
    return __builtin_amdgcn_rcpf(x);
}

// ===========================================================================
// K1: MFMA projections + norms + gate. NO LDS, NO barriers. Per-wave code is
// byte-identical to round 4 (proven 48 us, VGPR 72, no spill); only the
// WG shape changed: 1024 threads = 16 waves per WG, grid 512.
// Hypothesis under test: HW holds ~2 WGs in flight per CU regardless of
// resources -> fat WGs turn "2 WGs" into 32 resident waves instead of 8.
// ===========================================================================
extern "C" __global__ __launch_bounds__(1024, 4)
void engram_norm(const float* __restrict__ emb,   // [16,8192,32]
                 const float* __restrict__ hid,   // [16,8192,4,32]
                 const float* __restrict__ Wv,    // [32,32]
                 const float* __restrict__ bv,    // [32]
                 const float* __restrict__ Wk,    // [4,32,32]
                 const float* __restrict__ bk,    // [4,32]
                 const float* __restrict__ n1w,   // [4,32]
                 const float* __restrict__ n2w,   // [4,32]
                 const float* __restrict__ cnw,   // [4,32]
                 __half* __restrict__ xn_out,     // [16,8192,128] f16
                 float* __restrict__ val_out,     // [16,8192,32]
                 float* __restrict__ gate_out)    // [16,8192,4]
{
    const int tid = threadIdx.x;
    const int b   = blockIdx.x >> 5;      // 512 WGs = 16 b * 32 segments
    const int seg = blockIdx.x & 31;

    const int wv  = tid >> 6;     // 0..15 (wave = one 16-token MFMA m-tile)
    const int ln  = tid & 63;
    const int l15 = ln & 15;
    const int q   = ln >> 4;
    const int tw  = seg * 256 + wv * 16;  // wave's token base (always in-range)

    // hid stream: 16 independent float2 loads (channels 2*l15, 2*l15+1)
    float2 q2[4][4];
    #pragma unroll
    for (int r = 0; r < 4; ++r) {
        const int t = tw + q * 4 + r;
        const float2* qp = (const float2*)&hid[(size_t)((b << 13) + t) * 128];
        #pragma unroll
        for (int g = 0; g < 4; ++g) q2[r][g] = qp[g * 16 + l15];
    }

    // emb A-fragment (row = l15 -> token tw+l15, k-slice = q*8..q*8+7)
    float4 f0, f1;
    {
        const float4* p = (const float4*)&emb[(size_t)((b << 13) + tw + l15) * 32 + q * 8];
        f0 = p[0];
        f1 = p[1];
    }

    // biases + norm weights, float2 per lane (channels 2*l15, 2*l15+1)
    const float2 bv2 = ((const float2*)bv)[l15];
    float2 bk2[4], wn1[4], wn2[4], wcn[4];
    #pragma unroll
    for (int g = 0; g < 4; ++g) {
        bk2[g] = ((const float2*)(bk  + g * 32))[l15];
        wn1[g] = ((const float2*)(n1w + g * 32))[l15];
        wn2[g] = ((const float2*)(n2w + g * 32))[l15];
        wcn[g] = ((const float2*)(cnw + g * 32))[l15];
    }

    // ======== MFMA: 10 tiles, permuted columns ========
    f16x8 a;
    a[0] = (_Float16)f0.x; a[1] = (_Float16)f0.y;
    a[2] = (_Float16)f0.z; a[3] = (_Float16)f0.w;
    a[4] = (_Float16)f1.x; a[5] = (_Float16)f1.y;
    a[6] = (_Float16)f1.z; a[7] = (_Float16)f1.w;

    // Tile nt = 2p+e: column l15 <- weight row ch = 2*l15+e of (p==0?Wv:Wk[p-1]).
    // Lane's D pair (D[2p],D[2p+1]) = channels (2*l15, 2*l15+1).
    f32x4 D[10];
    #pragma unroll
    for (int nt = 0; nt < 10; ++nt) {
        const int e = nt & 1, p = nt >> 1;
        const int ch = 2 * l15 + e;
        const float* wrow = (p == 0) ? &Wv[ch * 32] : &Wk[((p - 1) * 32 + ch) * 32];
        float4 w0 = ((const float4*)wrow)[q * 2];
        float4 w1 = ((const float4*)wrow)[q * 2 + 1];
        f16x8 bf;
        bf[0] = (_Float16)w0.x; bf[1] = (_Float16)w0.y;
        bf[2] = (_Float16)w0.z; bf[3] = (_Float16)w0.w;
        bf[4] = (_Float16)w1.x; bf[5] = (_Float16)w1.y;
        bf[6] = (_Float16)w1.z; bf[7] = (_Float16)w1.w;
        const float bias = (p == 0) ? (e ? bv2.y : bv2.x)
                                    : (e ? bk2[p - 1].y : bk2[p - 1].x);
        f32x4 c = {bias, bias, bias, bias};
        D[nt] = __builtin_amdgcn_mfma_f32_16x16x32_f16(a, bf, c, 0, 0, 0);
    }

    // ======== norms + gate + x_norm; stream results straight to global ======
    #pragma unroll
    for (int r = 0; r < 4; ++r) {
        const int ti = tw + q * 4 + r;
        const float V0 = D[0][r], V1 = D[1][r];
        float msv = redsum16(V0 * V0 + V1 * V1);   // Σ value² over 32 ch
        float gs[4];
        float xnv[4][2];
        #pragma unroll
        for (int g = 0; g < 4; ++g) {
            const float K0 = D[2 + 2 * g][r], K1v = D[3 + 2 * g][r];
            const float q0 = q2[r][g].x, q1 = q2[r][g].y;
            float msk = redsum16(K0 * K0 + K1v * K1v);
            float msq = redsum16(q0 * q0 + q1 * q1);
            float dr  = redsum16(K0 * wn1[g].x * q0 * wn2[g].x
                               + K1v * wn1[g].y * q1 * wn2[g].y);
            float rk = rsqrtf(msk * (1.f / 32.f) + EPS);
            float rq = rsqrtf(msq * (1.f / 32.f) + EPS);
            float dot = dr * rk * rq * 0.17677669529663689f;   // /sqrt(32)
            float sa = sqrtf(fmaxf(fabsf(dot), 1e-6f));
            float gate = fast_rcp(1.f + __expf(-copysignf(sa, dot)));
            gs[g] = gate;
            float sc = gate * rsqrtf(gate * gate * msv * (1.f / 32.f) + EPS);
            xnv[g][0] = sc * V0 * wcn[g].x;
            xnv[g][1] = sc * V1 * wcn[g].y;
        }
        __half* xrow = xn_out + (size_t)((b << 13) + ti) * 128;
        #pragma unroll
        for (int g = 0; g < 4; ++g) {
            *(__half2*)&xrow[g * 32 + 2 * l15] = __floats2half2_rn(xnv[g][0], xnv[g][1]);
        }
        *(float2*)&val_out[(size_t)((b << 13) + ti) * 32 + 2 * l15] = make_float2(V0, V1);
        if (l15 < 4) {
            float gsel = (l15 == 0) ? gs[0] : (l15 == 1) ? gs[1]
                       : (l15 == 2) ? gs[2] : gs[3];
            gate_out[(size_t)((b << 13) + ti) * 4 + l15] = gsel;
        }
    }
}

// ===========================================================================
// K2: dilated depthwise conv + SiLU + gated residual. Same per-thread math
// as round 4/5; WG shape 1024 threads, grid 512, 8 slabs. No LDS.
// ===========================================================================
extern "C" __global__ __launch_bounds__(1024, 4)
void engram_conv(const __half* __restrict__ xn,   // [16,8192,128] f16
                 const float* __restrict__ val,   // [16,8192,32]
                 const float* __restrict__ gate,  // [16,8192,4]
                 const float* __restrict__ cw,    // [128,1,4]
                 float* __restrict__ out)         // [16,8192,128]
{
    const int tid = threadIdx.x;
    const int c4  = (tid & 31) << 2;   // channel quad — slab-stride keeps it fixed
    const int g   = c4 >> 5;

    const float4* cw4p = (const float4*)cw;
    const float4 w0 = cw4p[c4 + 0];
    const float4 w1 = cw4p[c4 + 1];
    const float4 w2 = cw4p[c4 + 2];
    const float4 w3 = cw4p[c4 + 3];

    int gid = blockIdx.x * 1024 + tid;
    #pragma unroll
    for (int it = 0; it < 8; ++it, gid += K2_SLAB) {
        const int t = (gid >> 5) & 8191;
        const int b = gid >> 18;
        const size_t row = (size_t)((b << 13) + t);

        float y0 = 0.f, y1 = 0.f, y2 = 0.f, y3 = 0.f;
        #pragma unroll
        for (int k = 0; k < 4; ++k) {
            const int tp  = t - HALO + 3 * k;
            const float m = (tp >= 0) ? 1.f : 0.f;    // causal zero-pad
            const int tpc = tp < 0 ? 0 : tp;
            const float2 rv = *(const float2*)&xn[(size_t)((b << 13) + tpc) * 128 + c4];
            float2 a01 = __half22float2(*(const __half2*)&rv.x);
            float2 a23 = __half22float2(*(const __half2*)&rv.y);
            const float wk0 = (k == 0) ? w0.x : (k == 1) ? w0.y : (k == 2) ? w0.z : w0.w;
            const float wk1 = (k == 0) ? w1.x : (k == 1) ? w1.y : (k == 2) ? w1.z : w1.w;
            const float wk2 = (k == 0) ? w2.x : (k == 1) ? w2.y : (k == 2) ? w2.z : w2.w;
            const float wk3 = (k == 0) ? w3.x : (k == 1) ? w3.y : (k == 2) ? w3.z : w3.w;
            y0 = fmaf(m * a01.x, wk0, y0);
            y1 = fmaf(m * a01.y, wk1, y1);
            y2 = fmaf(m * a23.x, wk2, y2);
            y3 = fmaf(m * a23.y, wk3, y3);
        }
        const float gg = gate[row * 4 + g];
        const f32x4 v  = *(const f32x4*)&val[row * 32 + (c4 & 31)];
        float4 o;
        o.x = gg * v[0] + y0 * fast_rcp(1.f + __expf(-y0));
        o.y = gg * v[1] + y1 * fast_rcp(1.f + __expf(-y1));
        o.z = gg * v[2] + y2 * fast_rcp(1.f + __expf(-y2));
        o.w = gg * v[3] + y3 * fast_rcp(1.f + __expf(-y3));
        *(float4*)&out[row * 128 + c4] = o;
    }
}

// ===========================================================================
// Fallback: round-0 fused kernel (proven), used only if workspace too small.
// ===========================================================================
extern "C" __global__ __launch_bounds__(320, 3)
void engram_fused(const float* __restrict__ emb,
                  const float* __restrict__ hid,
                  const float* __restrict__ Wv,
                  const float* __restrict__ bv,
                  const float* __restrict__ Wk,
                  const float* __restrict__ bk,
                  const float* __restrict__ n1w,
                  const float* __restrict__ n2w,
                  const float* __restrict__ cnw,
                  const float* __restrict__ cw,
                  float* __restrict__ out)
{
    __shared__ __align__(16) __half s_xn[NTOK * XSTR];
    __shared__ __align__(16) float  s_val[TT * VSTR];
    __shared__ float  s_gate[TT * 4];

    const int tid  = threadIdx.x;
    const int b    = blockIdx.x >> 7;
    const int tile = blockIdx.x & 127;
    const int t0   = tile * TT;

    const int wv  = tid >> 6;
    const int ln  = tid & 63;
    const int l15 = ln & 15;
    const int q   = ln >> 4;
    const int ibase = wv * 16 + q * 4;

    float2 q2[4][4];
    float  okm[4];
    #pragma unroll
    for (int r = 0; r < 4; ++r) {
        int t = t0 - HALO + ibase + r;
        okm[r] = (t >= 0 && t < 8192) ? 1.f : 0.f;
        int tc = t < 0 ? 0 : (t > 8191 ? 8191 : t);
        const float2* qp = (const float2*)&hid[(size_t)((b << 13) + tc) * 128];
        #pragma unroll
        for (int g = 0; g < 4; ++g) q2[r][g] = qp[g * 16 + l15];
    }

    float4 f0, f1;
    float amask;
    {
        const int tA = t0 - HALO + wv * 16 + l15;
        amask = (tA >= 0 && tA < 8192) ? 1.f : 0.f;
        const int tAc = tA < 0 ? 0 : (tA > 8191 ? 8191 : tA);
        const float4* p = (const float4*)&emb[(size_t)((b << 13) + tAc) * 32 + q * 8];
        f0 = p[0];
        f1 = p[1];
    }

    const float2 bv2 = ((const float2*)bv)[l15];
    float2 bk2[4], wn1[4], wn2[4], wcn[4];
    #pragma unroll
    for (int g = 0; g < 4; ++g) {
        bk2[g] = ((const float2*)(bk  + g * 32))[l15];
        wn1[g] = ((const float2*)(n1w + g * 32))[l15];
        wn2[g] = ((const float2*)(n2w + g * 32))[l15];
        wcn[g] = ((const float2*)(cnw + g * 32))[l15];
    }

    f16x8 a;
    a[0] = (_Float16)(amask * f0.x); a[1] = (_Float16)(amask * f0.y);
    a[2] = (_Float16)(amask * f0.z); a[3] = (_Float16)(amask * f0.w);
    a[4] = (_Float16)(amask * f1.x); a[5] = (_Float16)(amask * f1.y);
    a[6] = (_Float16)(amask * f1.z); a[7] = (_Float16)(amask * f1.w);

    f32x4 D[10];
    #pragma unroll
    for (int nt = 0; nt < 10; ++nt) {
        const int e = nt & 1, p = nt >> 1;
        const int ch = 2 * l15 + e;
        const float* wrow = (p == 0) ? &Wv[ch * 32] : &Wk[((p - 1) * 32 + ch) * 32];
        float4 w0 = ((const float4*)wrow)[q * 2];
        float4 w1 = ((const float4*)wrow)[q * 2 + 1];
        f16x8 bf;
        bf[0] = (_Float16)w0.x; bf[1] = (_Float16)w0.y;
        bf[2] = (_Float16)w0.z; bf[3] = (_Float16)w0.w;
        bf[4] = (_Float16)w1.x; bf[5] = (_Float16)w1.y;
        bf[6] = (_Float16)w1.z; bf[7] = (_Float16)w1.w;
        const float bias = (p == 0) ? (e ? bv2.y : bv2.x)
                                    : (e ? bk2[p - 1].y : bk2[p - 1].x);
        f32x4 c = {bias, bias, bias, bias};
        D[nt] = __builtin_amdgcn_mfma_f32_16x16x32_f16(a, bf, c, 0, 0, 0);
    }

    #pragma unroll
    for (int r = 0; r < 4; ++r) {
        const int i = ibase + r;
        const float V0 = D[0][r], V1 = D[1][r];
        float msv = redsum16(V0 * V0 + V1 * V1);
        float gs[4];
        float xnv[4][2];
        #pragma unroll
        for (int g = 0; g < 4; ++g) {
            const float K0 = D[2 + 2 * g][r], K1v = D[3 + 2 * g][r];
            const float q0 = q2[r][g].x * okm[r], q1 = q2[r][g].y * okm[r];
            float msk = redsum16(K0 * K0 + K1v * K1v);
            float msq = redsum16(q0 * q0 + q1 * q1);
            float dr  = redsum16(K0 * wn1[g].x * q0 * wn2[g].x
                               + K1v * wn1[g].y * q1 * wn2[g].y);
            float rk = rsqrtf(msk * (1.f / 32.f) + EPS);
            float rq = rsqrtf(msq * (1.f / 32.f) + EPS);
            float dot = dr * rk * rq * 0.17677669529663689f;
            float sa = sqrtf(fmaxf(fabsf(dot), 1e-6f));
            float gate = fast_rcp(1.f + __expf(-copysignf(sa, dot)));
            gs[g] = gate;
            float sc = gate * rsqrtf(gate * gate * msv * (1.f / 32.f) + EPS);
            xnv[g][0] = sc * V0 * wcn[g].x;
            xnv[g][1] = sc * V1 * wcn[g].y;
        }
        if (i < NTOK) {
            #pragma unroll
            for (int g = 0; g < 4; ++g) {
                __half2 h2 = __floats2half2_rn(okm[r] * xnv[g][0], okm[r] * xnv[g][1]);
                *(__half2*)&s_xn[i * XSTR + g * 32 + 2 * l15] = h2;
            }
            if (i >= HALO) {
                const int j = i - HALO;
                *(float2*)&s_val[j * VSTR + 2 * l15] = make_float2(V0, V1);
                if (l15 < 4) {
                    float gsel = (l15 == 0) ? gs[0] : (l15 == 1) ? gs[1]
                               : (l15 == 2) ? gs[2] : gs[3];
                    s_gate[j * 4 + l15] = gsel;
                }
            }
        }
    }
    __syncthreads();

    const float4* cw4p = (const float4*)cw;
    for (int idx = tid; idx < TT * 32; idx += 320) {
        const int j  = idx >> 5;
        const int c4 = (idx & 31) << 2;
        float4 w0 = cw4p[c4 + 0];
        float4 w1 = cw4p[c4 + 1];
        float4 w2 = cw4p[c4 + 2];
        float4 w3 = cw4p[c4 + 3];
        float y0 = 0.f, y1 = 0.f, y2 = 0.f, y3 = 0.f;
        #pragma unroll
        for (int k = 0; k < 4; ++k) {
            const __half2* xp = (const __half2*)&s_xn[(j + 3 * k) * XSTR + c4];
            float2 a01 = __half22float2(xp[0]);
            float2 a23 = __half22float2(xp[1]);
            const float wk0 = (k == 0) ? w0.x : (k == 1) ? w0.y : (k == 2) ? w0.z : w0.w;
            const float wk1 = (k == 0) ? w1.x : (k == 1) ? w1.y : (k == 2) ? w1.z : w1.w;
            const float wk2 = (k == 0) ? w2.x : (k == 1) ? w2.y : (k == 2) ? w2.z : w2.w;
            const float wk3 = (k == 0) ? w3.x : (k == 1) ? w3.y : (k == 2) ? w3.z : w3.w;
            y0 = fmaf(a01.x, wk0, y0);
            y1 = fmaf(a01.y, wk1, y1);
            y2 = fmaf(a23.x, wk2, y2);
            y3 = fmaf(a23.y, wk3, y3);
        }
        const float g  = s_gate[j * 4 + (c4 >> 5)];
        const f32x4 v  = *(const f32x4*)&s_val[j * VSTR + (c4 & 31)];
        float4 o;
        o.x = g * v[0] + y0 * fast_rcp(1.f + __expf(-y0));
        o.y = g * v[1] + y1 * fast_rcp(1.f + __expf(-y1));
        o.z = g * v[2] + y2 * fast_rcp(1.f + __expf(-y2));
        o.w = g * v[3] + y3 * fast_rcp(1.f + __expf(-y3));
        *(float4*)&out[(size_t)((b << 13) + t0 + j) * 128 + c4] = o;
    }
}

extern "C" void kernel_launch(void* const* d_in, const int* in_sizes, int n_in,
                              void* d_out, int out_size, void* d_ws, size_t ws_size,
                              hipStream_t stream) {
    const float* emb = (const float*)d_in[0];
    const float* hid = (const float*)d_in[1];
    const float* Wv  = (const float*)d_in[2];
    const float* bvp = (const float*)d_in[3];
    const float* Wk  = (const float*)d_in[4];
    const float* bkp = (const float*)d_in[5];
    const float* n1  = (const float*)d_in[6];
    const float* n2  = (const float*)d_in[7];
    const float* cn  = (const float*)d_in[8];
    const float* cwp = (const float*)d_in[9];
    float* out = (float*)d_out;

    const size_t xn_bytes   = (size_t)16 * 8192 * 128 * sizeof(__half);  // 33.6 MB
    const size_t val_bytes  = (size_t)16 * 8192 * 32 * sizeof(float);    // 16.8 MB
    const size_t gate_bytes = (size_t)16 * 8192 * 4 * sizeof(float);     //  2.1 MB
    const size_t need = xn_bytes + val_bytes + gate_bytes;               // 52.4 MB

    if (d_ws != nullptr && ws_size >= need) {
        __half* xn  = (__half*)d_ws;
        float* val  = (float*)((char*)d_ws + xn_bytes);
        float* gate = (float*)((char*)d_ws + xn_bytes + val_bytes);
        engram_norm<<<dim3(GRID1), dim3(1024), 0, stream>>>(
            emb, hid, Wv, bvp, Wk, bkp, n1, n2, cn, xn, val, gate);
        engram_conv<<<dim3(GRID2), dim3(1024), 0, stream>>>(
            xn, val, gate, cwp, out);
    } else {
        engram_fused<<<dim3(16 * 128), dim3(320), 0, stream>>>(
            emb, hid, Wv, bvp, Wk, bkp, n1, n2, cn, cwp, out);
    }
}

// Round 7
// 167.026 us; speedup vs baseline: 1.1582x; 1.1024x over previous
//
#include <hip/hip_runtime.h>
#include <hip/hip_fp16.h>

#define TT    64        // output tokens per tile (fused fallback)
#define HALO  9         // (KERNEL_SIZE-1)*DILATION
#define NTOK  73        // TT + HALO
#define XSTR  132       // s_xn row stride in halves (fused fallback)
#define VSTR  36        // s_val row stride in floats (fused fallback)
#define EPS   1.1920929e-07f

#define GRID1  2048     // K1: r4-proven shape — 2048 WGs x 256 thr
#define NM     683      // K2 token quads per (b, residue): 12*683 = 8196 >= 8192
#define GRID2  4098     // K2: 16 b * 3 r * 683 m * 32 c4 / 256 thr

typedef __attribute__((ext_vector_type(8))) _Float16 f16x8;
typedef __attribute__((ext_vector_type(4))) float f32x4;

// sum over each 16-lane row via DPP rotate-butterfly: pure VALU, no LDS pipe.
template<int CTRL>
__device__ __forceinline__ float dpp_add(float x) {
    int y = __builtin_amdgcn_update_dpp(0, __float_as_int(x), CTRL, 0xF, 0xF, true);
    return x + __int_as_float(y);
}
__device__ __forceinline__ float redsum16(float x) {
    x = dpp_add<0x128>(x);   // row_ror:8
    x = dpp_add<0x124>(x);   // row_ror:4
    x = dpp_add<0x122>(x);   // row_ror:2
    x = dpp_add<0x121>(x);   // row_ror:1
    return x;
}

__device__ __forceinline__ float fast_rcp(float x) {
    return __builtin_amdgcn_rcpf(x);
}

// ===========================================================================
// K0 (prep): pack the 10 MFMA B-fragments (Wv, Wk) into f16, laid out exactly
// as K1's lanes read them: element idx = nt*64 + l15*4 + q, 8 halves each.
// One tiny block; weights are identical for all 8192 K1 waves, so the
// ~120 cvt/pack VALU per wave move here (run once).
// ===========================================================================
extern "C" __global__ __launch_bounds__(640)
void engram_prep(const float* __restrict__ Wv,    // [32,32]
                 const float* __restrict__ Wk,    // [4,32,32]
                 __half* __restrict__ wfrag)      // [640*8] halves
{
    const int idx = threadIdx.x;        // 0..639 = nt*64 + l15*4 + q
    const int nt  = idx >> 6;
    const int l15 = (idx >> 2) & 15;
    const int q   = idx & 3;
    const int e = nt & 1, p = nt >> 1;
    const int ch = 2 * l15 + e;
    const float* wrow = (p == 0) ? &Wv[ch * 32] : &Wk[((p - 1) * 32 + ch) * 32];
    float4 w0 = ((const float4*)wrow)[q * 2];
    float4 w1 = ((const float4*)wrow)[q * 2 + 1];
    __half2* dst = (__half2*)(wfrag + (size_t)idx * 8);
    dst[0] = __floats2half2_rn(w0.x, w0.y);   // rne — identical to (_Float16) cast
    dst[1] = __floats2half2_rn(w0.z, w0.w);
    dst[2] = __floats2half2_rn(w1.x, w1.y);
    dst[3] = __floats2half2_rn(w1.z, w1.w);
}

// ===========================================================================
// K1: MFMA projections + norms + gate. NO LDS, NO barriers. r4-proven shape
// (256 thr, 2048 WGs, wave = one 16-token m-tile). Changes vs r4:
//   - B-fragments loaded pre-packed f16 (one dwordx4) — no per-wave cvt
//   - rk*rq merged into one rsqrt(msk'*msq')
// ===========================================================================
extern "C" __global__ __launch_bounds__(256)
void engram_norm(const float* __restrict__ emb,   // [16,8192,32]
                 const float* __restrict__ hid,   // [16,8192,4,32]
                 const float* __restrict__ bv,    // [32]
                 const float* __restrict__ bk,    // [4,32]
                 const float* __restrict__ n1w,   // [4,32]
                 const float* __restrict__ n2w,   // [4,32]
                 const float* __restrict__ cnw,   // [4,32]
                 const __half* __restrict__ wfrag,// [640*8] packed B-frags
                 __half* __restrict__ xn_out,     // [16,8192,128] f16
                 float* __restrict__ val_out,     // [16,8192,32]
                 float* __restrict__ gate_out)    // [16,8192,4]
{
    const int tid  = threadIdx.x;
    const int b    = blockIdx.x >> 7;     // grid = 16 * 128
    const int tile = blockIdx.x & 127;
    const int t0   = tile * 64;

    const int wv  = tid >> 6;     // 0..3 (wave = one 16-token MFMA tile)
    const int ln  = tid & 63;
    const int l15 = ln & 15;
    const int q   = ln >> 4;
    const int tw  = t0 + wv * 16;         // wave's token base (always in-range)

    // hid stream: 16 independent float2 loads (channels 2*l15, 2*l15+1)
    float2 q2[4][4];
    #pragma unroll
    for (int r = 0; r < 4; ++r) {
        const int t = tw + q * 4 + r;
        const float2* qp = (const float2*)&hid[(size_t)((b << 13) + t) * 128];
        #pragma unroll
        for (int g = 0; g < 4; ++g) q2[r][g] = qp[g * 16 + l15];
    }

    // emb A-fragment (row = l15 -> token tw+l15, k-slice = q*8..q*8+7)
    float4 f0, f1;
    {
        const float4* p = (const float4*)&emb[(size_t)((b << 13) + tw + l15) * 32 + q * 8];
        f0 = p[0];
        f1 = p[1];
    }

    // biases + norm weights, float2 per lane (channels 2*l15, 2*l15+1)
    const float2 bv2 = ((const float2*)bv)[l15];
    float2 bk2[4], wn1[4], wn2[4], wcn[4];
    #pragma unroll
    for (int g = 0; g < 4; ++g) {
        bk2[g] = ((const float2*)(bk  + g * 32))[l15];
        wn1[g] = ((const float2*)(n1w + g * 32))[l15];
        wn2[g] = ((const float2*)(n2w + g * 32))[l15];
        wcn[g] = ((const float2*)(cnw + g * 32))[l15];
    }

    // ======== MFMA: 10 tiles, permuted columns, pre-packed B ========
    f16x8 a;
    a[0] = (_Float16)f0.x; a[1] = (_Float16)f0.y;
    a[2] = (_Float16)f0.z; a[3] = (_Float16)f0.w;
    a[4] = (_Float16)f1.x; a[5] = (_Float16)f1.y;
    a[6] = (_Float16)f1.z; a[7] = (_Float16)f1.w;

    // Tile nt = 2p+e: column l15 <- weight row ch = 2*l15+e of (p==0?Wv:Wk[p-1]).
    // Lane's D pair (D[2p],D[2p+1]) = channels (2*l15, 2*l15+1).
    const f16x8* wf = (const f16x8*)wfrag;
    f32x4 D[10];
    #pragma unroll
    for (int nt = 0; nt < 10; ++nt) {
        const int e = nt & 1, p = nt >> 1;
        f16x8 bf = wf[nt * 64 + l15 * 4 + q];   // one 16B load, zero cvt
        const float bias = (p == 0) ? (e ? bv2.y : bv2.x)
                                    : (e ? bk2[p - 1].y : bk2[p - 1].x);
        f32x4 c = {bias, bias, bias, bias};
        D[nt] = __builtin_amdgcn_mfma_f32_16x16x32_f16(a, bf, c, 0, 0, 0);
    }

    // ======== norms + gate + x_norm; stream results straight to global ======
    #pragma unroll
    for (int r = 0; r < 4; ++r) {
        const int ti = tw + q * 4 + r;
        const float V0 = D[0][r], V1 = D[1][r];
        float msv = redsum16(V0 * V0 + V1 * V1);   // Σ value² over 32 ch
        float gs[4];
        float xnv[4][2];
        #pragma unroll
        for (int g = 0; g < 4; ++g) {
            const float K0 = D[2 + 2 * g][r], K1v = D[3 + 2 * g][r];
            const float q0 = q2[r][g].x, q1 = q2[r][g].y;
            float msk = redsum16(K0 * K0 + K1v * K1v);
            float msq = redsum16(q0 * q0 + q1 * q1);
            float dr  = redsum16(K0 * wn1[g].x * q0 * wn2[g].x
                               + K1v * wn1[g].y * q1 * wn2[g].y);
            // rsqrt(a)*rsqrt(b) == rsqrt(a*b) for a,b>0 — one trans op
            float rkq = rsqrtf((msk * (1.f / 32.f) + EPS) * (msq * (1.f / 32.f) + EPS));
            float dot = dr * rkq * 0.17677669529663689f;   // /sqrt(32)
            float sa = sqrtf(fmaxf(fabsf(dot), 1e-6f));
            float gate = fast_rcp(1.f + __expf(-copysignf(sa, dot)));
            gs[g] = gate;
            float sc = gate * rsqrtf(gate * gate * msv * (1.f / 32.f) + EPS);
            xnv[g][0] = sc * V0 * wcn[g].x;
            xnv[g][1] = sc * V1 * wcn[g].y;
        }
        __half* xrow = xn_out + (size_t)((b << 13) + ti) * 128;
        #pragma unroll
        for (int g = 0; g < 4; ++g) {
            *(__half2*)&xrow[g * 32 + 2 * l15] = __floats2half2_rn(xnv[g][0], xnv[g][1]);
        }
        *(float2*)&val_out[(size_t)((b << 13) + ti) * 32 + 2 * l15] = make_float2(V0, V1);
        if (l15 < 4) {
            float gsel = (l15 == 0) ? gs[0] : (l15 == 1) ? gs[1]
                       : (l15 == 2) ? gs[2] : gs[3];
            gate_out[(size_t)((b << 13) + ti) * 4 + l15] = gsel;
        }
    }
}

// ===========================================================================
// K2: dilated depthwise conv + SiLU + gated residual. Stride-3 token quad:
// thread owns outputs {t0, t0+3, t0+6, t0+9}, t0 = 12m + r (bijective over
// [0,8192) via t = 12m + 3i + r). The 4 outputs share taps: 7 tap loads
// replace 16. fma order (k ascending) preserved — bit-identical math.
// ===========================================================================
extern "C" __global__ __launch_bounds__(256)
void engram_conv(const __half* __restrict__ xn,   // [16,8192,128] f16
                 const float* __restrict__ val,   // [16,8192,32]
                 const float* __restrict__ gate,  // [16,8192,4]
                 const float* __restrict__ cw,    // [128,1,4]
                 float* __restrict__ out)         // [16,8192,128]
{
    const int gid = blockIdx.x * 256 + threadIdx.x;  // exactly 16*3*683*32 threads
    const int c4i = gid & 31;
    const int c4  = c4i << 2;                        // channels c4..c4+3
    const int g   = c4 >> 5;
    int rest = gid >> 5;                             // b*3*683 + r*683 + m
    const int m  = rest % NM;
    rest /= NM;
    const int r  = rest % 3;
    const int b  = rest / 3;
    const int t0 = 12 * m + r;                       // outputs t0 + 3i, i=0..3

    const float4* cw4p = (const float4*)cw;
    const float4 w0 = cw4p[c4 + 0];
    const float4 w1 = cw4p[c4 + 1];
    const float4 w2 = cw4p[c4 + 2];
    const float4 w3 = cw4p[c4 + 3];

    // taps j=0..6 at rows t0-9+3j; causal zero for row<0; clamp-high rows
    // only ever feed masked-out (t>=8192) outputs.
    float2 tap01[7], tap23[7];
    #pragma unroll
    for (int j = 0; j < 7; ++j) {
        const int tr = t0 - 9 + 3 * j;
        const float mj = (tr >= 0) ? 1.f : 0.f;
        const int trc = tr < 0 ? 0 : (tr > 8191 ? 8191 : tr);
        const __half2* xp = (const __half2*)&xn[(size_t)((b << 13) + trc) * 128 + c4];
        float2 a01 = __half22float2(xp[0]);
        float2 a23 = __half22float2(xp[1]);
        tap01[j] = make_float2(mj * a01.x, mj * a01.y);
        tap23[j] = make_float2(mj * a23.x, mj * a23.y);
    }

    #pragma unroll
    for (int i = 0; i < 4; ++i) {
        const int t = t0 + 3 * i;
        if (t < 8192) {
            // y(t_i) uses taps i..i+3 with weights k=0..3 (ascending fma chain)
            float y0 = 0.f, y1 = 0.f, y2 = 0.f, y3 = 0.f;
            #pragma unroll
            for (int k = 0; k < 4; ++k) {
                const float wk0 = (k == 0) ? w0.x : (k == 1) ? w0.y : (k == 2) ? w0.z : w0.w;
                const float wk1 = (k == 0) ? w1.x : (k == 1) ? w1.y : (k == 2) ? w1.z : w1.w;
                const float wk2 = (k == 0) ? w2.x : (k == 1) ? w2.y : (k == 2) ? w2.z : w2.w;
                const float wk3 = (k == 0) ? w3.x : (k == 1) ? w3.y : (k == 2) ? w3.z : w3.w;
                y0 = fmaf(tap01[i + k].x, wk0, y0);
                y1 = fmaf(tap01[i + k].y, wk1, y1);
                y2 = fmaf(tap23[i + k].x, wk2, y2);
                y3 = fmaf(tap23[i + k].y, wk3, y3);
            }
            const size_t row = (size_t)((b << 13) + t);
            const float gg = gate[row * 4 + g];
            const f32x4 v  = *(const f32x4*)&val[row * 32 + (c4 & 31)];
            float4 o;
            o.x = gg * v[0] + y0 * fast_rcp(1.f + __expf(-y0));
            o.y = gg * v[1] + y1 * fast_rcp(1.f + __expf(-y1));
            o.z = gg * v[2] + y2 * fast_rcp(1.f + __expf(-y2));
            o.w = gg * v[3] + y3 * fast_rcp(1.f + __expf(-y3));
            *(float4*)&out[row * 128 + c4] = o;
        }
    }
}

// ===========================================================================
// Fallback: round-0 fused kernel (proven), used only if workspace too small.
// ===========================================================================
extern "C" __global__ __launch_bounds__(320, 3)
void engram_fused(const float* __restrict__ emb,
                  const float* __restrict__ hid,
                  const float* __restrict__ Wv,
                  const float* __restrict__ bv,
                  const float* __restrict__ Wk,
                  const float* __restrict__ bk,
                  const float* __restrict__ n1w,
                  const float* __restrict__ n2w,
                  const float* __restrict__ cnw,
                  const float* __restrict__ cw,
                  float* __restrict__ out)
{
    __shared__ __align__(16) __half s_xn[NTOK * XSTR];
    __shared__ __align__(16) float  s_val[TT * VSTR];
    __shared__ float  s_gate[TT * 4];

    const int tid  = threadIdx.x;
    const int b    = blockIdx.x >> 7;
    const int tile = blockIdx.x & 127;
    const int t0   = tile * TT;

    const int wv  = tid >> 6;
    const int ln  = tid & 63;
    const int l15 = ln & 15;
    const int q   = ln >> 4;
    const int ibase = wv * 16 + q * 4;

    float2 q2[4][4];
    float  okm[4];
    #pragma unroll
    for (int r = 0; r < 4; ++r) {
        int t = t0 - HALO + ibase + r;
        okm[r] = (t >= 0 && t < 8192) ? 1.f : 0.f;
        int tc = t < 0 ? 0 : (t > 8191 ? 8191 : t);
        const float2* qp = (const float2*)&hid[(size_t)((b << 13) + tc) * 128];
        #pragma unroll
        for (int g = 0; g < 4; ++g) q2[r][g] = qp[g * 16 + l15];
    }

    float4 f0, f1;
    float amask;
    {
        const int tA = t0 - HALO + wv * 16 + l15;
        amask = (tA >= 0 && tA < 8192) ? 1.f : 0.f;
        const int tAc = tA < 0 ? 0 : (tA > 8191 ? 8191 : tA);
        const float4* p = (const float4*)&emb[(size_t)((b << 13) + tAc) * 32 + q * 8];
        f0 = p[0];
        f1 = p[1];
    }

    const float2 bv2 = ((const float2*)bv)[l15];
    float2 bk2[4], wn1[4], wn2[4], wcn[4];
    #pragma unroll
    for (int g = 0; g < 4; ++g) {
        bk2[g] = ((const float2*)(bk  + g * 32))[l15];
        wn1[g] = ((const float2*)(n1w + g * 32))[l15];
        wn2[g] = ((const float2*)(n2w + g * 32))[l15];
        wcn[g] = ((const float2*)(cnw + g * 32))[l15];
    }

    f16x8 a;
    a[0] = (_Float16)(amask * f0.x); a[1] = (_Float16)(amask * f0.y);
    a[2] = (_Float16)(amask * f0.z); a[3] = (_Float16)(amask * f0.w);
    a[4] = (_Float16)(amask * f1.x); a[5] = (_Float16)(amask * f1.y);
    a[6] = (_Float16)(amask * f1.z); a[7] = (_Float16)(amask * f1.w);

    f32x4 D[10];
    #pragma unroll
    for (int nt = 0; nt < 10; ++nt) {
        const int e = nt & 1, p = nt >> 1;
        const int ch = 2 * l15 + e;
        const float* wrow = (p == 0) ? &Wv[ch * 32] : &Wk[((p - 1) * 32 + ch) * 32];
        float4 w0 = ((const float4*)wrow)[q * 2];
        float4 w1 = ((const float4*)wrow)[q * 2 + 1];
        f16x8 bf;
        bf[0] = (_Float16)w0.x; bf[1] = (_Float16)w0.y;
        bf[2] = (_Float16)w0.z; bf[3] = (_Float16)w0.w;
        bf[4] = (_Float16)w1.x; bf[5] = (_Float16)w1.y;
        bf[6] = (_Float16)w1.z; bf[7] = (_Float16)w1.w;
        const float bias = (p == 0) ? (e ? bv2.y : bv2.x)
                                    : (e ? bk2[p - 1].y : bk2[p - 1].x);
        f32x4 c = {bias, bias, bias, bias};
        D[nt] = __builtin_amdgcn_mfma_f32_16x16x32_f16(a, bf, c, 0, 0, 0);
    }

    #pragma unroll
    for (int r = 0; r < 4; ++r) {
        const int i = ibase + r;
        const float V0 = D[0][r], V1 = D[1][r];
        float msv = redsum16(V0 * V0 + V1 * V1);
        float gs[4];
        float xnv[4][2];
        #pragma unroll
        for (int g = 0; g < 4; ++g) {
            const float K0 = D[2 + 2 * g][r], K1v = D[3 + 2 * g][r];
            const float q0 = q2[r][g].x * okm[r], q1 = q2[r][g].y * okm[r];
            float msk = redsum16(K0 * K0 + K1v * K1v);
            float msq = redsum16(q0 * q0 + q1 * q1);
            float dr  = redsum16(K0 * wn1[g].x * q0 * wn2[g].x
                               + K1v * wn1[g].y * q1 * wn2[g].y);
            float rk = rsqrtf(msk * (1.f / 32.f) + EPS);
            float rq = rsqrtf(msq * (1.f / 32.f) + EPS);
            float dot = dr * rk * rq * 0.17677669529663689f;
            float sa = sqrtf(fmaxf(fabsf(dot), 1e-6f));
            float gate = fast_rcp(1.f + __expf(-copysignf(sa, dot)));
            gs[g] = gate;
            float sc = gate * rsqrtf(gate * gate * msv * (1.f / 32.f) + EPS);
            xnv[g][0] = sc * V0 * wcn[g].x;
            xnv[g][1] = sc * V1 * wcn[g].y;
        }
        if (i < NTOK) {
            #pragma unroll
            for (int g = 0; g < 4; ++g) {
                __half2 h2 = __floats2half2_rn(okm[r] * xnv[g][0], okm[r] * xnv[g][1]);
                *(__half2*)&s_xn[i * XSTR + g * 32 + 2 * l15] = h2;
            }
            if (i >= HALO) {
                const int j = i - HALO;
                *(float2*)&s_val[j * VSTR + 2 * l15] = make_float2(V0, V1);
                if (l15 < 4) {
                    float gsel = (l15 == 0) ? gs[0] : (l15 == 1) ? gs[1]
                               : (l15 == 2) ? gs[2] : gs[3];
                    s_gate[j * 4 + l15] = gsel;
                }
            }
        }
    }
    __syncthreads();

    const float4* cw4p = (const float4*)cw;
    for (int idx = tid; idx < TT * 32; idx += 320) {
        const int j  = idx >> 5;
        const int c4 = (idx & 31) << 2;
        float4 w0 = cw4p[c4 + 0];
        float4 w1 = cw4p[c4 + 1];
        float4 w2 = cw4p[c4 + 2];
        float4 w3 = cw4p[c4 + 3];
        float y0 = 0.f, y1 = 0.f, y2 = 0.f, y3 = 0.f;
        #pragma unroll
        for (int k = 0; k < 4; ++k) {
            const __half2* xp = (const __half2*)&s_xn[(j + 3 * k) * XSTR + c4];
            float2 a01 = __half22float2(xp[0]);
            float2 a23 = __half22float2(xp[1]);
            const float wk0 = (k == 0) ? w0.x : (k == 1) ? w0.y : (k == 2) ? w0.z : w0.w;
            const float wk1 = (k == 0) ? w1.x : (k == 1) ? w1.y : (k == 2) ? w1.z : w1.w;
            const float wk2 = (k == 0) ? w2.x : (k == 1) ? w2.y : (k == 2) ? w2.z : w2.w;
            const float wk3 = (k == 0) ? w3.x : (k == 1) ? w3.y : (k == 2) ? w3.z : w3.w;
            y0 = fmaf(a01.x, wk0, y0);
            y1 = fmaf(a01.y, wk1, y1);
            y2 = fmaf(a23.x, wk2, y2);
            y3 = fmaf(a23.y, wk3, y3);
        }
        const float g  = s_gate[j * 4 + (c4 >> 5)];
        const f32x4 v  = *(const f32x4*)&s_val[j * VSTR + (c4 & 31)];
        float4 o;
        o.x = g * v[0] + y0 * fast_rcp(1.f + __expf(-y0));
        o.y = g * v[1] + y1 * fast_rcp(1.f + __expf(-y1));
        o.z = g * v[2] + y2 * fast_rcp(1.f + __expf(-y2));
        o.w = g * v[3] + y3 * fast_rcp(1.f + __expf(-y3));
        *(float4*)&out[(size_t)((b << 13) + t0 + j) * 128 + c4] = o;
    }
}

extern "C" void kernel_launch(void* const* d_in, const int* in_sizes, int n_in,
                              void* d_out, int out_size, void* d_ws, size_t ws_size,
                              hipStream_t stream) {
    const float* emb = (const float*)d_in[0];
    const float* hid = (const float*)d_in[1];
    const float* Wv  = (const float*)d_in[2];
    const float* bvp = (const float*)d_in[3];
    const float* Wk  = (const float*)d_in[4];
    const float* bkp = (const float*)d_in[5];
    const float* n1  = (const float*)d_in[6];
    const float* n2  = (const float*)d_in[7];
    const float* cn  = (const float*)d_in[8];
    const float* cwp = (const float*)d_in[9];
    float* out = (float*)d_out;

    const size_t xn_bytes   = (size_t)16 * 8192 * 128 * sizeof(__half);  // 33.6 MB
    const size_t val_bytes  = (size_t)16 * 8192 * 32 * sizeof(float);    // 16.8 MB
    const size_t gate_bytes = (size_t)16 * 8192 * 4 * sizeof(float);     //  2.1 MB
    const size_t wf_bytes   = (size_t)640 * 8 * sizeof(__half);          //  10 KB
    const size_t need = xn_bytes + val_bytes + gate_bytes + wf_bytes;

    if (d_ws != nullptr && ws_size >= need) {
        __half* xn  = (__half*)d_ws;
        float* val  = (float*)((char*)d_ws + xn_bytes);
        float* gate = (float*)((char*)d_ws + xn_bytes + val_bytes);
        __half* wf  = (__half*)((char*)d_ws + xn_bytes + val_bytes + gate_bytes);
        engram_prep<<<dim3(1), dim3(640), 0, stream>>>(Wv, Wk, wf);
        engram_norm<<<dim3(GRID1), dim3(256), 0, stream>>>(
            emb, hid, bvp, bkp, n1, n2, cn, wf, xn, val, gate);
        engram_conv<<<dim3(GRID2), dim3(256), 0, stream>>>(
            xn, val, gate, cwp, out);
    } else {
        engram_fused<<<dim3(16 * 128), dim3(320), 0, stream>>>(
            emb, hid, Wv, bvp, Wk, bkp, n1, n2, cn, cwp, out);
    }
}

// Round 8
// 165.740 us; speedup vs baseline: 1.1672x; 1.0078x over previous
//
#include <hip/hip_runtime.h>
#include <hip/hip_fp16.h>

#define TT    64        // output tokens per tile (fused fallback)
#define HALO  9         // (KERNEL_SIZE-1)*DILATION
#define NTOK  73        // TT + HALO
#define XSTR  132       // s_xn row stride in halves (fused fallback)
#define VSTR  36        // s_val row stride in floats (fused fallback)
#define EPS   1.1920929e-07f

#define GRID1  2048     // K1: 2048 WGs x 256 thr (wave = one 16-token m-tile)
#define NM     683      // K2 token quads per (b, residue): 12*683 = 8196 >= 8192
#define GRID2  4098     // K2: 16 b * 3 r * 683 m * 32 c4 / 256 thr

typedef __attribute__((ext_vector_type(8))) _Float16 f16x8;
typedef __attribute__((ext_vector_type(4))) float f32x4;

// sum over each 16-lane row via DPP rotate-butterfly: pure VALU, no LDS pipe.
template<int CTRL>
__device__ __forceinline__ float dpp_add(float x) {
    int y = __builtin_amdgcn_update_dpp(0, __float_as_int(x), CTRL, 0xF, 0xF, true);
    return x + __int_as_float(y);
}
__device__ __forceinline__ float redsum16(float x) {
    x = dpp_add<0x128>(x);   // row_ror:8
    x = dpp_add<0x124>(x);   // row_ror:4
    x = dpp_add<0x122>(x);   // row_ror:2
    x = dpp_add<0x121>(x);   // row_ror:1
    return x;
}

__device__ __forceinline__ float fast_rcp(float x) {
    return __builtin_amdgcn_rcpf(x);
}

// ===========================================================================
// K0 (prep): pack the 10 MFMA B-fragments (Wv, Wk) into f16 in K1 lane order,
// and pre-multiply w12 = n1w .* n2w (they only ever appear as a product).
// ===========================================================================
extern "C" __global__ __launch_bounds__(640)
void engram_prep(const float* __restrict__ Wv,    // [32,32]
                 const float* __restrict__ Wk,    // [4,32,32]
                 const float* __restrict__ n1w,   // [4,32]
                 const float* __restrict__ n2w,   // [4,32]
                 __half* __restrict__ wfrag,      // [640*8] halves
                 float* __restrict__ w12)         // [4*32]
{
    const int idx = threadIdx.x;        // 0..639 = nt*64 + l15*4 + q
    if (idx < 128) w12[idx] = n1w[idx] * n2w[idx];
    const int nt  = idx >> 6;
    const int l15 = (idx >> 2) & 15;
    const int q   = idx & 3;
    const int e = nt & 1, p = nt >> 1;
    const int ch = 2 * l15 + e;
    const float* wrow = (p == 0) ? &Wv[ch * 32] : &Wk[((p - 1) * 32 + ch) * 32];
    float4 w0 = ((const float4*)wrow)[q * 2];
    float4 w1 = ((const float4*)wrow)[q * 2 + 1];
    __half2* dst = (__half2*)(wfrag + (size_t)idx * 8);
    dst[0] = __floats2half2_rn(w0.x, w0.y);   // rne — identical to (_Float16) cast
    dst[1] = __floats2half2_rn(w0.z, w0.w);
    dst[2] = __floats2half2_rn(w1.x, w1.y);
    dst[3] = __floats2half2_rn(w1.z, w1.w);
}

// ===========================================================================
// K1: MFMA projections + norms + gate. NO LDS, NO barriers.
// (256,1): VGPR cap 256 — round 7's 68-reg allocation forced the ~41 result
// registers of the load wave-front to be reused, serializing loads into a
// load->wait->load chain (~23k-cycle wave lifetime for ~2.6k cycles of issue).
// With the full working set (~140 regs) resident, all loads fly concurrently.
// r1/r5 regressions were caps BELOW the working set (spill); this is the
// opposite: budget ABOVE it. Spill tripwire: WRITE_SIZE > 53 MB.
// ===========================================================================
extern "C" __global__ __launch_bounds__(256, 1)
void engram_norm(const float* __restrict__ emb,   // [16,8192,32]
                 const float* __restrict__ hid,   // [16,8192,4,32]
                 const float* __restrict__ bv,    // [32]
                 const float* __restrict__ bk,    // [4,32]
                 const float* __restrict__ w12,   // [4,32] = n1w.*n2w
                 const float* __restrict__ cnw,   // [4,32]
                 const __half* __restrict__ wfrag,// [640*8] packed B-frags
                 __half* __restrict__ xn_out,     // [16,8192,128] f16
                 float* __restrict__ val_out,     // [16,8192,32]
                 float* __restrict__ gate_out)    // [16,8192,4]
{
    const int tid  = threadIdx.x;
    const int b    = blockIdx.x >> 7;     // grid = 16 * 128
    const int tile = blockIdx.x & 127;
    const int t0   = tile * 64;

    const int wv  = tid >> 6;     // 0..3 (wave = one 16-token MFMA tile)
    const int ln  = tid & 63;
    const int l15 = ln & 15;
    const int q   = ln >> 4;
    const int tw  = t0 + wv * 16;         // wave's token base (always in-range)

    // hid stream: 16 independent float2 loads (channels 2*l15, 2*l15+1)
    float2 q2[4][4];
    #pragma unroll
    for (int r = 0; r < 4; ++r) {
        const int t = tw + q * 4 + r;
        const float2* qp = (const float2*)&hid[(size_t)((b << 13) + t) * 128];
        #pragma unroll
        for (int g = 0; g < 4; ++g) q2[r][g] = qp[g * 16 + l15];
    }

    // emb A-fragment (row = l15 -> token tw+l15, k-slice = q*8..q*8+7)
    float4 f0, f1;
    {
        const float4* p = (const float4*)&emb[(size_t)((b << 13) + tw + l15) * 32 + q * 8];
        f0 = p[0];
        f1 = p[1];
    }

    // biases + norm weights, float2 per lane (channels 2*l15, 2*l15+1)
    const float2 bv2 = ((const float2*)bv)[l15];
    float2 bk2[4], wnn[4], wcn[4];
    #pragma unroll
    for (int g = 0; g < 4; ++g) {
        bk2[g] = ((const float2*)(bk  + g * 32))[l15];
        wnn[g] = ((const float2*)(w12 + g * 32))[l15];
        wcn[g] = ((const float2*)(cnw + g * 32))[l15];
    }

    // ======== MFMA: 10 tiles, permuted columns, pre-packed B ========
    f16x8 a;
    a[0] = (_Float16)f0.x; a[1] = (_Float16)f0.y;
    a[2] = (_Float16)f0.z; a[3] = (_Float16)f0.w;
    a[4] = (_Float16)f1.x; a[5] = (_Float16)f1.y;
    a[6] = (_Float16)f1.z; a[7] = (_Float16)f1.w;

    // Tile nt = 2p+e: column l15 <- weight row ch = 2*l15+e of (p==0?Wv:Wk[p-1]).
    // Lane's D pair (D[2p],D[2p+1]) = channels (2*l15, 2*l15+1).
    const f16x8* wf = (const f16x8*)wfrag;
    f32x4 D[10];
    #pragma unroll
    for (int nt = 0; nt < 10; ++nt) {
        const int e = nt & 1, p = nt >> 1;
        f16x8 bf = wf[nt * 64 + l15 * 4 + q];   // one 16B load, zero cvt
        const float bias = (p == 0) ? (e ? bv2.y : bv2.x)
                                    : (e ? bk2[p - 1].y : bk2[p - 1].x);
        f32x4 c = {bias, bias, bias, bias};
        D[nt] = __builtin_amdgcn_mfma_f32_16x16x32_f16(a, bf, c, 0, 0, 0);
    }

    // ======== norms + gate + x_norm; stream results straight to global ======
    #pragma unroll
    for (int r = 0; r < 4; ++r) {
        const int ti = tw + q * 4 + r;
        const float V0 = D[0][r], V1 = D[1][r];
        float msv = redsum16(V0 * V0 + V1 * V1);   // Σ value² over 32 ch
        float gs[4];
        float xnv[4][2];
        #pragma unroll
        for (int g = 0; g < 4; ++g) {
            const float K0 = D[2 + 2 * g][r], K1v = D[3 + 2 * g][r];
            const float q0 = q2[r][g].x, q1 = q2[r][g].y;
            float msk = redsum16(K0 * K0 + K1v * K1v);
            float msq = redsum16(q0 * q0 + q1 * q1);
            float dr  = redsum16(K0 * wnn[g].x * q0 + K1v * wnn[g].y * q1);
            // rsqrt(a)*rsqrt(b) == rsqrt(a*b) for a,b>0 — one trans op
            float rkq = rsqrtf((msk * (1.f / 32.f) + EPS) * (msq * (1.f / 32.f) + EPS));
            float dot = dr * rkq * 0.17677669529663689f;   // /sqrt(32)
            float sa = sqrtf(fmaxf(fabsf(dot), 1e-6f));
            float gate = fast_rcp(1.f + __expf(-copysignf(sa, dot)));
            gs[g] = gate;
            float sc = gate * rsqrtf(gate * gate * msv * (1.f / 32.f) + EPS);
            xnv[g][0] = sc * V0 * wcn[g].x;
            xnv[g][1] = sc * V1 * wcn[g].y;
        }
        __half* xrow = xn_out + (size_t)((b << 13) + ti) * 128;
        #pragma unroll
        for (int g = 0; g < 4; ++g) {
            *(__half2*)&xrow[g * 32 + 2 * l15] = __floats2half2_rn(xnv[g][0], xnv[g][1]);
        }
        *(float2*)&val_out[(size_t)((b << 13) + ti) * 32 + 2 * l15] = make_float2(V0, V1);
        if (l15 < 4) {
            float gsel = (l15 == 0) ? gs[0] : (l15 == 1) ? gs[1]
                       : (l15 == 2) ? gs[2] : gs[3];
            gate_out[(size_t)((b << 13) + ti) * 4 + l15] = gsel;
        }
    }
}

// ===========================================================================
// K2: dilated depthwise conv + SiLU + gated residual. Stride-3 token quad:
// thread owns outputs {t0, t0+3, t0+6, t0+9}, t0 = 12m + r. 7 shared tap
// loads replace 16. (256,1): same load-parallelism fix as K1 (~13 scattered
// loads per thread).
// ===========================================================================
extern "C" __global__ __launch_bounds__(256, 1)
void engram_conv(const __half* __restrict__ xn,   // [16,8192,128] f16
                 const float* __restrict__ val,   // [16,8192,32]
                 const float* __restrict__ gate,  // [16,8192,4]
                 const float* __restrict__ cw,    // [128,1,4]
                 float* __restrict__ out)         // [16,8192,128]
{
    const int gid = blockIdx.x * 256 + threadIdx.x;  // exactly 16*3*683*32 threads
    const int c4i = gid & 31;
    const int c4  = c4i << 2;                        // channels c4..c4+3
    const int g   = c4 >> 5;
    int rest = gid >> 5;                             // b*3*683 + r*683 + m
    const int m  = rest % NM;
    rest /= NM;
    const int r  = rest % 3;
    const int b  = rest / 3;
    const int t0 = 12 * m + r;                       // outputs t0 + 3i, i=0..3

    const float4* cw4p = (const float4*)cw;
    const float4 w0 = cw4p[c4 + 0];
    const float4 w1 = cw4p[c4 + 1];
    const float4 w2 = cw4p[c4 + 2];
    const float4 w3 = cw4p[c4 + 3];

    // taps j=0..6 at rows t0-9+3j; causal zero for row<0; clamp-high rows
    // only ever feed masked-out (t>=8192) outputs.
    float2 tap01[7], tap23[7];
    #pragma unroll
    for (int j = 0; j < 7; ++j) {
        const int tr = t0 - 9 + 3 * j;
        const float mj = (tr >= 0) ? 1.f : 0.f;
        const int trc = tr < 0 ? 0 : (tr > 8191 ? 8191 : tr);
        const __half2* xp = (const __half2*)&xn[(size_t)((b << 13) + trc) * 128 + c4];
        float2 a01 = __half22float2(xp[0]);
        float2 a23 = __half22float2(xp[1]);
        tap01[j] = make_float2(mj * a01.x, mj * a01.y);
        tap23[j] = make_float2(mj * a23.x, mj * a23.y);
    }

    #pragma unroll
    for (int i = 0; i < 4; ++i) {
        const int t = t0 + 3 * i;
        if (t < 8192) {
            // y(t_i) uses taps i..i+3 with weights k=0..3 (ascending fma chain)
            float y0 = 0.f, y1 = 0.f, y2 = 0.f, y3 = 0.f;
            #pragma unroll
            for (int k = 0; k < 4; ++k) {
                const float wk0 = (k == 0) ? w0.x : (k == 1) ? w0.y : (k == 2) ? w0.z : w0.w;
                const float wk1 = (k == 0) ? w1.x : (k == 1) ? w1.y : (k == 2) ? w1.z : w1.w;
                const float wk2 = (k == 0) ? w2.x : (k == 1) ? w2.y : (k == 2) ? w2.z : w2.w;
                const float wk3 = (k == 0) ? w3.x : (k == 1) ? w3.y : (k == 2) ? w3.z : w3.w;
                y0 = fmaf(tap01[i + k].x, wk0, y0);
                y1 = fmaf(tap01[i + k].y, wk1, y1);
                y2 = fmaf(tap23[i + k].x, wk2, y2);
                y3 = fmaf(tap23[i + k].y, wk3, y3);
            }
            const size_t row = (size_t)((b << 13) + t);
            const float gg = gate[row * 4 + g];
            const f32x4 v  = *(const f32x4*)&val[row * 32 + (c4 & 31)];
            float4 o;
            o.x = gg * v[0] + y0 * fast_rcp(1.f + __expf(-y0));
            o.y = gg * v[1] + y1 * fast_rcp(1.f + __expf(-y1));
            o.z = gg * v[2] + y2 * fast_rcp(1.f + __expf(-y2));
            o.w = gg * v[3] + y3 * fast_rcp(1.f + __expf(-y3));
            *(float4*)&out[row * 128 + c4] = o;
        }
    }
}

// ===========================================================================
// Fallback: round-0 fused kernel (proven), used only if workspace too small.
// ===========================================================================
extern "C" __global__ __launch_bounds__(320, 3)
void engram_fused(const float* __restrict__ emb,
                  const float* __restrict__ hid,
                  const float* __restrict__ Wv,
                  const float* __restrict__ bv,
                  const float* __restrict__ Wk,
                  const float* __restrict__ bk,
                  const float* __restrict__ n1w,
                  const float* __restrict__ n2w,
                  const float* __restrict__ cnw,
                  const float* __restrict__ cw,
                  float* __restrict__ out)
{
    __shared__ __align__(16) __half s_xn[NTOK * XSTR];
    __shared__ __align__(16) float  s_val[TT * VSTR];
    __shared__ float  s_gate[TT * 4];

    const int tid  = threadIdx.x;
    const int b    = blockIdx.x >> 7;
    const int tile = blockIdx.x & 127;
    const int t0   = tile * TT;

    const int wv  = tid >> 6;
    const int ln  = tid & 63;
    const int l15 = ln & 15;
    const int q   = ln >> 4;
    const int ibase = wv * 16 + q * 4;

    float2 q2[4][4];
    float  okm[4];
    #pragma unroll
    for (int r = 0; r < 4; ++r) {
        int t = t0 - HALO + ibase + r;
        okm[r] = (t >= 0 && t < 8192) ? 1.f : 0.f;
        int tc = t < 0 ? 0 : (t > 8191 ? 8191 : t);
        const float2* qp = (const float2*)&hid[(size_t)((b << 13) + tc) * 128];
        #pragma unroll
        for (int g = 0; g < 4; ++g) q2[r][g] = qp[g * 16 + l15];
    }

    float4 f0, f1;
    float amask;
    {
        const int tA = t0 - HALO + wv * 16 + l15;
        amask = (tA >= 0 && tA < 8192) ? 1.f : 0.f;
        const int tAc = tA < 0 ? 0 : (tA > 8191 ? 8191 : tA);
        const float4* p = (const float4*)&emb[(size_t)((b << 13) + tAc) * 32 + q * 8];
        f0 = p[0];
        f1 = p[1];
    }

    const float2 bv2 = ((const float2*)bv)[l15];
    float2 bk2[4], wn1[4], wn2[4], wcn[4];
    #pragma unroll
    for (int g = 0; g < 4; ++g) {
        bk2[g] = ((const float2*)(bk  + g * 32))[l15];
        wn1[g] = ((const float2*)(n1w + g * 32))[l15];
        wn2[g] = ((const float2*)(n2w + g * 32))[l15];
        wcn[g] = ((const float2*)(cnw + g * 32))[l15];
    }

    f16x8 a;
    a[0] = (_Float16)(amask * f0.x); a[1] = (_Float16)(amask * f0.y);
    a[2] = (_Float16)(amask * f0.z); a[3] = (_Float16)(amask * f0.w);
    a[4] = (_Float16)(amask * f1.x); a[5] = (_Float16)(amask * f1.y);
    a[6] = (_Float16)(amask * f1.z); a[7] = (_Float16)(amask * f1.w);

    f32x4 D[10];
    #pragma unroll
    for (int nt = 0; nt < 10; ++nt) {
        const int e = nt & 1, p = nt >> 1;
        const int ch = 2 * l15 + e;
        const float* wrow = (p == 0) ? &Wv[ch * 32] : &Wk[((p - 1) * 32 + ch) * 32];
        float4 w0 = ((const float4*)wrow)[q * 2];
        float4 w1 = ((const float4*)wrow)[q * 2 + 1];
        f16x8 bf;
        bf[0] = (_Float16)w0.x; bf[1] = (_Float16)w0.y;
        bf[2] = (_Float16)w0.z; bf[3] = (_Float16)w0.w;
        bf[4] = (_Float16)w1.x; bf[5] = (_Float16)w1.y;
        bf[6] = (_Float16)w1.z; bf[7] = (_Float16)w1.w;
        const float bias = (p == 0) ? (e ? bv2.y : bv2.x)
                                    : (e ? bk2[p - 1].y : bk2[p - 1].x);
        f32x4 c = {bias, bias, bias, bias};
        D[nt] = __builtin_amdgcn_mfma_f32_16x16x32_f16(a, bf, c, 0, 0, 0);
    }

    #pragma unroll
    for (int r = 0; r < 4; ++r) {
        const int i = ibase + r;
        const float V0 = D[0][r], V1 = D[1][r];
        float msv = redsum16(V0 * V0 + V1 * V1);
        float gs[4];
        float xnv[4][2];
        #pragma unroll
        for (int g = 0; g < 4; ++g) {
            const float K0 = D[2 + 2 * g][r], K1v = D[3 + 2 * g][r];
            const float q0 = q2[r][g].x * okm[r], q1 = q2[r][g].y * okm[r];
            float msk = redsum16(K0 * K0 + K1v * K1v);
            float msq = redsum16(q0 * q0 + q1 * q1);
            float dr  = redsum16(K0 * wn1[g].x * q0 * wn2[g].x
                               + K1v * wn1[g].y * q1 * wn2[g].y);
            float rk = rsqrtf(msk * (1.f / 32.f) + EPS);
            float rq = rsqrtf(msq * (1.f / 32.f) + EPS);
            float dot = dr * rk * rq * 0.17677669529663689f;
            float sa = sqrtf(fmaxf(fabsf(dot), 1e-6f));
            float gate = fast_rcp(1.f + __expf(-copysignf(sa, dot)));
            gs[g] = gate;
            float sc = gate * rsqrtf(gate * gate * msv * (1.f / 32.f) + EPS);
            xnv[g][0] = sc * V0 * wcn[g].x;
            xnv[g][1] = sc * V1 * wcn[g].y;
        }
        if (i < NTOK) {
            #pragma unroll
            for (int g = 0; g < 4; ++g) {
                __half2 h2 = __floats2half2_rn(okm[r] * xnv[g][0], okm[r] * xnv[g][1]);
                *(__half2*)&s_xn[i * XSTR + g * 32 + 2 * l15] = h2;
            }
            if (i >= HALO) {
                const int j = i - HALO;
                *(float2*)&s_val[j * VSTR + 2 * l15] = make_float2(V0, V1);
                if (l15 < 4) {
                    float gsel = (l15 == 0) ? gs[0] : (l15 == 1) ? gs[1]
                               : (l15 == 2) ? gs[2] : gs[3];
                    s_gate[j * 4 + l15] = gsel;
                }
            }
        }
    }
    __syncthreads();

    const float4* cw4p = (const float4*)cw;
    for (int idx = tid; idx < TT * 32; idx += 320) {
        const int j  = idx >> 5;
        const int c4 = (idx & 31) << 2;
        float4 w0 = cw4p[c4 + 0];
        float4 w1 = cw4p[c4 + 1];
        float4 w2 = cw4p[c4 + 2];
        float4 w3 = cw4p[c4 + 3];
        float y0 = 0.f, y1 = 0.f, y2 = 0.f, y3 = 0.f;
        #pragma unroll
        for (int k = 0; k < 4; ++k) {
            const __half2* xp = (const __half2*)&s_xn[(j + 3 * k) * XSTR + c4];
            float2 a01 = __half22float2(xp[0]);
            float2 a23 = __half22float2(xp[1]);
            const float wk0 = (k == 0) ? w0.x : (k == 1) ? w0.y : (k == 2) ? w0.z : w0.w;
            const float wk1 = (k == 0) ? w1.x : (k == 1) ? w1.y : (k == 2) ? w1.z : w1.w;
            const float wk2 = (k == 0) ? w2.x : (k == 1) ? w2.y : (k == 2) ? w2.z : w2.w;
            const float wk3 = (k == 0) ? w3.x : (k == 1) ? w3.y : (k == 2) ? w3.z : w3.w;
            y0 = fmaf(a01.x, wk0, y0);
            y1 = fmaf(a01.y, wk1, y1);
            y2 = fmaf(a23.x, wk2, y2);
            y3 = fmaf(a23.y, wk3, y3);
        }
        const float g  = s_gate[j * 4 + (c4 >> 5)];
        const f32x4 v  = *(const f32x4*)&s_val[j * VSTR + (c4 & 31)];
        float4 o;
        o.x = g * v[0] + y0 * fast_rcp(1.f + __expf(-y0));
        o.y = g * v[1] + y1 * fast_rcp(1.f + __expf(-y1));
        o.z = g * v[2] + y2 * fast_rcp(1.f + __expf(-y2));
        o.w = g * v[3] + y3 * fast_rcp(1.f + __expf(-y3));
        *(float4*)&out[(size_t)((b << 13) + t0 + j) * 128 + c4] = o;
    }
}

extern "C" void kernel_launch(void* const* d_in, const int* in_sizes, int n_in,
                              void* d_out, int out_size, void* d_ws, size_t ws_size,
                              hipStream_t stream) {
    const float* emb = (const float*)d_in[0];
    const float* hid = (const float*)d_in[1];
    const float* Wv  = (const float*)d_in[2];
    const float* bvp = (const float*)d_in[3];
    const float* Wk  = (const float*)d_in[4];
    const float* bkp = (const float*)d_in[5];
    const float* n1  = (const float*)d_in[6];
    const float* n2  = (const float*)d_in[7];
    const float* cn  = (const float*)d_in[8];
    const float* cwp = (const float*)d_in[9];
    float* out = (float*)d_out;

    const size_t xn_bytes   = (size_t)16 * 8192 * 128 * sizeof(__half);  // 33.6 MB
    const size_t val_bytes  = (size_t)16 * 8192 * 32 * sizeof(float);    // 16.8 MB
    const size_t gate_bytes = (size_t)16 * 8192 * 4 * sizeof(float);     //  2.1 MB
    const size_t wf_bytes   = (size_t)640 * 8 * sizeof(__half);          //  10 KB
    const size_t w12_bytes  = (size_t)128 * sizeof(float);               // 512 B
    const size_t need = xn_bytes + val_bytes + gate_bytes + wf_bytes + w12_bytes;

    if (d_ws != nullptr && ws_size >= need) {
        __half* xn  = (__half*)d_ws;
        float* val  = (float*)((char*)d_ws + xn_bytes);
        float* gate = (float*)((char*)d_ws + xn_bytes + val_bytes);
        __half* wf  = (__half*)((char*)d_ws + xn_bytes + val_bytes + gate_bytes);
        float* w12  = (float*)((char*)d_ws + xn_bytes + val_bytes + gate_bytes + wf_bytes);
        engram_prep<<<dim3(1), dim3(640), 0, stream>>>(Wv, Wk, n1, n2, wf, w12);
        engram_norm<<<dim3(GRID1), dim3(256), 0, stream>>>(
            emb, hid, bvp, bkp, w12, cn, wf, xn, val, gate);
        engram_conv<<<dim3(GRID2), dim3(256), 0, stream>>>(
            xn, val, gate, cwp, out);
    } else {
        engram_fused<<<dim3(16 * 128), dim3(320), 0, stream>>>(
            emb, hid, Wv, bvp, Wk, bkp, n1, n2, cn, cwp, out);
    }
}